// Round 7
// baseline (78.355 us; speedup 1.0000x reference)
//
#include <hip/hip_runtime.h>

#define NN 2048
#define NH 4
#define COLS 256   // NH*F_OUT

typedef __attribute__((ext_vector_type(8))) short short8;
typedef __attribute__((ext_vector_type(4))) float f32x4;
typedef __attribute__((ext_vector_type(4))) int i32x4;
typedef __attribute__((ext_vector_type(4))) unsigned u32x4;

__device__ __forceinline__ unsigned cvtpk(float lo, float hi) {
  unsigned r;
  asm("v_cvt_pk_bf16_f32 %0, %1, %2" : "=v"(r) : "v"(lo), "v"(hi));
  return r;
}
__device__ __forceinline__ unsigned pack16(i32x4 a, i32x4 b, i32x4 c, i32x4 d) {
  unsigned m = 0;
  #pragma unroll
  for (int e = 0; e < 4; ++e) {
    m |= (a[e] != 0 ? 1u : 0u) << e;
    m |= (b[e] != 0 ? 1u : 0u) << (e + 4);
    m |= (c[e] != 0 ? 1u : 0u) << (e + 8);
    m |= (d[e] != 0 ? 1u : 0u) << (e + 12);
  }
  return m;
}

// ---------------------------------------------------------------------------
// Kernel 1: h = X @ W (f32 accum). grid 1024 x 256, 8 rows/block.
//   hB : bf16, MFMA B-fragment-contiguous:
//        chunk = ((bh*64 + jc)*4 + t)*64 + (grp*16 + fl), 8 ushorts/chunk
//        holds h[n = jc*32+grp*8+e][f = t*16+fl].
//   s_src/s_dst : f32 [bh][n], PRE-SCALED by log2(e).
// Thread tid owns column tid (head = tid>>6, f = tid&63) for its 8 rows, so
// the hB flush needs no LDS transpose (flush col == compute col).
// ---------------------------------------------------------------------------
__global__ __launch_bounds__(256) void k1_prep(
    const float* __restrict__ nf, const float* __restrict__ W,
    const float* __restrict__ att, ushort* __restrict__ hB,
    float* __restrict__ s_src, float* __restrict__ s_dst)
{
  const int tid = threadIdx.x;
  const int head = tid >> 6, lane = tid & 63;
  const int bid = blockIdx.x;
  const int m0 = bid * 8;

  float w[64];
  #pragma unroll
  for (int f = 0; f < 64; ++f) w[f] = W[f * COLS + tid];   // coalesced

  const float LOG2E = 1.4426950408889634f;
  const float asrc = att[head * 128 + lane] * LOG2E;
  const float adst = att[head * 128 + 64 + lane] * LOG2E;

  __shared__ float xs[512];
  xs[tid]       = nf[m0 * 64 + tid];
  xs[tid + 256] = nf[m0 * 64 + 256 + tid];
  __syncthreads();

  float hv[8];
  #pragma unroll
  for (int rr = 0; rr < 8; ++rr) {
    float acc = 0.f;
    #pragma unroll
    for (int f = 0; f < 64; ++f) acc = fmaf(xs[rr * 64 + f], w[f], acc);
    hv[rr] = acc;
    float vs = acc * asrc, vd = acc * adst;
    #pragma unroll
    for (int off = 32; off > 0; off >>= 1) {
      vs += __shfl_xor(vs, off);
      vd += __shfl_xor(vd, off);
    }
    if (lane == 0) {
      const int m = m0 + rr;
      const int b = m >> 11, n = m & (NN - 1);
      s_src[(b * NH + head) * NN + n] = vs;
      s_dst[(b * NH + head) * NN + n] = vd;
    }
  }

  // flush: thread's own 8 rows, own column -> one 16B store
  const int b   = m0 >> 11;
  const int n0  = m0 & (NN - 1);
  const int jc  = n0 >> 5;
  const int grp = (n0 >> 3) & 3;
  const int t   = (tid >> 4) & 3, fl = tid & 15;
  uint4 vv;
  vv.x = cvtpk(hv[0], hv[1]);
  vv.y = cvtpk(hv[2], hv[3]);
  vv.z = cvtpk(hv[4], hv[5]);
  vv.w = cvtpk(hv[6], hv[7]);
  const size_t chunk =
      (((size_t)(b * NH + head) * 64 + jc) * 4 + t) * 64 + (grp * 16 + fl);
  *(uint4*)(hB + chunk * 8) = vv;
}

// ---------------------------------------------------------------------------
// Kernel 2: fused mask + leakyrelu + softmax + P@H via MFMA 16x16x32 bf16.
// grid 512 (XCD-swizzled) x 1024 thr = 16 waves; 16 i-rows/block ->
// 2 blocks/CU (LDS 64000B, VGPR<=64 via launch_bounds). wave = (head, js).
// adj staged once coalesced -> bit-masks in LDS, double-buffered, 4 steps.
// ---------------------------------------------------------------------------
__global__ __launch_bounds__(1024, 8) void k2_main(
    const int* __restrict__ adj, const ushort* __restrict__ hB,
    const float* __restrict__ s_src, const float* __restrict__ s_dst,
    float* __restrict__ out)
{
  const int tid = threadIdx.x;
  const int wv  = tid >> 6;
  const int w   = wv >> 2;            // head
  const int js  = wv & 3;             // j-quarter
  const int l   = tid & 63;
  int bid = blockIdx.x;
  bid = (bid & 7) * 64 + (bid >> 3);  // bijective XCD swizzle (grid=512)
  const int b   = bid >> 7;
  const int i0  = (bid & 127) << 4;

  const int bh   = b * NH + w;
  const int r16  = l & 15;
  const int grp  = l >> 4;
  const int koff = grp << 3;

  const float ssl = s_src[bh * NN + i0 + r16];
  const float*  sdp = s_dst + bh * NN;
  const ushort* hbW = hB + (size_t)bh * 131072 + l * 8;

  // staging role (tid < 512): (sjs, srow, 16 cols at soct*16)
  const int sjs = tid >> 7, srow = (tid >> 3) & 15, soct = tid & 7;
  const int* sbase = adj + ((size_t)b * NN + i0 + srow) * NN + sjs * 512 + soct * 16;

  __shared__ unsigned abits[2][4][16][5];        // padded: conflict-free reads
  __shared__ float red[NH][3][5][4][64];         // scalar layout: stride-1/lane

  const short8 ones = {(short)0x3F80, (short)0x3F80, (short)0x3F80, (short)0x3F80,
                       (short)0x3F80, (short)0x3F80, (short)0x3F80, (short)0x3F80};

  f32x4 acc[4];
  #pragma unroll
  for (int q = 0; q < 4; ++q) acc[q] = (f32x4){0.f, 0.f, 0.f, 0.f};
  f32x4 acd = (f32x4){0.f, 0.f, 0.f, 0.f};

  if (tid < 512) {
    const i32x4 ra0 = *(const i32x4*)(sbase + 0);
    const i32x4 ra1 = *(const i32x4*)(sbase + 4);
    const i32x4 ra2 = *(const i32x4*)(sbase + 8);
    const i32x4 ra3 = *(const i32x4*)(sbase + 12);
    ((ushort*)&abits[0][sjs][srow][0])[soct] = (ushort)pack16(ra0, ra1, ra2, ra3);
  }
  __syncthreads();

  #pragma unroll 1
  for (int s = 0; s < 4; ++s) {
    i32x4 ra0, ra1, ra2, ra3;
    if (s < 3 && tid < 512) {
      const int* sp = sbase + (s + 1) * 128;
      ra0 = *(const i32x4*)(sp + 0);
      ra1 = *(const i32x4*)(sp + 4);
      ra2 = *(const i32x4*)(sp + 8);
      ra3 = *(const i32x4*)(sp + 12);
    }
    const int cur = s & 1;

    #pragma unroll
    for (int q4 = 0; q4 < 4; ++q4) {
      const int jc = js * 16 + s * 4 + q4;
      const unsigned wlo = abits[cur][js][r16][q4];
      const int jb = jc * 32 + koff;
      const f32x4 sd0 = *(const f32x4*)(sdp + jb);
      const f32x4 sd1 = *(const f32x4*)(sdp + jb + 4);
      const ushort* hc = hbW + jc * 2048;
      const short8 hb0 = *(const short8*)(hc);
      const short8 hb1 = *(const short8*)(hc + 512);
      const short8 hb2 = *(const short8*)(hc + 1024);
      const short8 hb3 = *(const short8*)(hc + 1536);

      float pl[8];
      #pragma unroll
      for (int e = 0; e < 8; ++e) {
        const float sdv = (e < 4) ? sd0[e] : sd1[e - 4];
        float x = ssl + sdv;                 // pre-scaled by log2(e)
        x = fmaxf(x, 0.2f * x);
        const float p = __builtin_amdgcn_exp2f(x);
        pl[e] = ((wlo >> (koff + e)) & 1u) ? p : 0.f;
      }
      u32x4 pa;
      #pragma unroll
      for (int e2 = 0; e2 < 4; ++e2) pa[e2] = cvtpk(pl[2 * e2], pl[2 * e2 + 1]);
      union { u32x4 u; short8 s; } ca; ca.u = pa;
      const short8 pal = ca.s;

      acc[0] = __builtin_amdgcn_mfma_f32_16x16x32_bf16(pal, hb0, acc[0], 0, 0, 0);
      acc[1] = __builtin_amdgcn_mfma_f32_16x16x32_bf16(pal, hb1, acc[1], 0, 0, 0);
      acc[2] = __builtin_amdgcn_mfma_f32_16x16x32_bf16(pal, hb2, acc[2], 0, 0, 0);
      acc[3] = __builtin_amdgcn_mfma_f32_16x16x32_bf16(pal, hb3, acc[3], 0, 0, 0);
      acd    = __builtin_amdgcn_mfma_f32_16x16x32_bf16(pal, ones, acd,    0, 0, 0);
    }

    if (s < 3 && tid < 512)
      ((ushort*)&abits[cur ^ 1][sjs][srow][0])[soct] = (ushort)pack16(ra0, ra1, ra2, ra3);
    __syncthreads();
  }

  // cross-js reduction: one barrier, conflict-free scalar LDS
  if (js > 0) {
    #pragma unroll
    for (int t = 0; t < 4; ++t)
      #pragma unroll
      for (int r = 0; r < 4; ++r) red[w][js - 1][t][r][l] = acc[t][r];
    #pragma unroll
    for (int r = 0; r < 4; ++r) red[w][js - 1][4][r][l] = acd[r];
  }
  __syncthreads();

  if (js == 0) {
    #pragma unroll
    for (int src = 0; src < 3; ++src) {
      #pragma unroll
      for (int t = 0; t < 4; ++t)
        #pragma unroll
        for (int r = 0; r < 4; ++r) acc[t][r] += red[w][src][t][r][l];
      #pragma unroll
      for (int r = 0; r < 4; ++r) acd[r] += red[w][src][4][r][l];
    }
    float rl[4];
    #pragma unroll
    for (int r = 0; r < 4; ++r) rl[r] = 1.0f / acd[r];
    #pragma unroll
    for (int t = 0; t < 4; ++t) {
      #pragma unroll
      for (int r = 0; r < 4; ++r) {
        const int i = i0 + grp * 4 + r;
        const size_t oidx = ((size_t)(b * NN + i) * COLS) + w * 64 + t * 16 + r16;
        out[oidx] = acc[t][r] * rl[r];
      }
    }
  }
}

// ---------------------------------------------------------------------------
extern "C" void kernel_launch(void* const* d_in, const int* in_sizes, int n_in,
                              void* d_out, int out_size, void* d_ws, size_t ws_size,
                              hipStream_t stream) {
  const float* nf  = (const float*)d_in[0];
  const int*   adj = (const int*)d_in[1];
  const float* W   = (const float*)d_in[2];
  const float* att = (const float*)d_in[3];

  ushort* hB    = (ushort*)d_ws;                                  // 4 MB
  float*  s_src = (float*)((char*)d_ws + (size_t)16 * 64 * NN * 2);
  float*  s_dst = s_src + 16 * NN;

  hipLaunchKernelGGL(k1_prep, dim3(1024), dim3(256), 0, stream,
                     nf, W, att, hB, s_src, s_dst);
  hipLaunchKernelGGL(k2_main, dim3(512), dim3(1024), 0, stream,
                     adj, hB, s_src, s_dst, (float*)d_out);
}

// Round 8
// 56.047 us; speedup vs baseline: 1.3980x; 1.3980x over previous
//
#include <hip/hip_runtime.h>

#define NN 2048
#define NH 4
#define COLS 256   // NH*F_OUT

typedef __attribute__((ext_vector_type(8))) short short8;
typedef __attribute__((ext_vector_type(4))) float f32x4;
typedef __attribute__((ext_vector_type(4))) int i32x4;
typedef __attribute__((ext_vector_type(4))) unsigned u32x4;

__device__ __forceinline__ unsigned cvtpk(float lo, float hi) {
  unsigned r;
  asm("v_cvt_pk_bf16_f32 %0, %1, %2" : "=v"(r) : "v"(lo), "v"(hi));
  return r;
}
__device__ __forceinline__ unsigned pack16(i32x4 a, i32x4 b, i32x4 c, i32x4 d) {
  unsigned m = 0;
  #pragma unroll
  for (int e = 0; e < 4; ++e) {
    m |= (a[e] != 0 ? 1u : 0u) << e;
    m |= (b[e] != 0 ? 1u : 0u) << (e + 4);
    m |= (c[e] != 0 ? 1u : 0u) << (e + 8);
    m |= (d[e] != 0 ? 1u : 0u) << (e + 12);
  }
  return m;
}

// ---------------------------------------------------------------------------
// Kernel 1: h = X @ W (f32 accum). grid 1024 x 256, 8 rows/block.
//   hB : bf16, MFMA B-fragment-contiguous:
//        chunk = ((bh*64 + jc)*4 + t)*64 + (grp*16 + fl), 8 ushorts/chunk
//        holds h[n = jc*32+grp*8+e][f = t*16+fl].
//   s_src/s_dst : f32 [bh][n], PRE-SCALED by log2(e).
// ---------------------------------------------------------------------------
__global__ __launch_bounds__(256) void k1_prep(
    const float* __restrict__ nf, const float* __restrict__ W,
    const float* __restrict__ att, ushort* __restrict__ hB,
    float* __restrict__ s_src, float* __restrict__ s_dst)
{
  const int tid = threadIdx.x;
  const int head = tid >> 6, lane = tid & 63;
  const int bid = blockIdx.x;
  const int m0 = bid * 8;

  float w[64];
  #pragma unroll
  for (int f = 0; f < 64; ++f) w[f] = W[f * COLS + tid];   // coalesced

  const float LOG2E = 1.4426950408889634f;
  const float asrc = att[head * 128 + lane] * LOG2E;
  const float adst = att[head * 128 + 64 + lane] * LOG2E;

  __shared__ float xs[512];
  xs[tid]       = nf[m0 * 64 + tid];
  xs[tid + 256] = nf[m0 * 64 + 256 + tid];
  __syncthreads();

  float hv[8];
  #pragma unroll
  for (int rr = 0; rr < 8; ++rr) {
    float acc = 0.f;
    #pragma unroll
    for (int f = 0; f < 64; ++f) acc = fmaf(xs[rr * 64 + f], w[f], acc);
    hv[rr] = acc;
    float vs = acc * asrc, vd = acc * adst;
    #pragma unroll
    for (int off = 32; off > 0; off >>= 1) {
      vs += __shfl_xor(vs, off);
      vd += __shfl_xor(vd, off);
    }
    if (lane == 0) {
      const int m = m0 + rr;
      const int b = m >> 11, n = m & (NN - 1);
      s_src[(b * NH + head) * NN + n] = vs;
      s_dst[(b * NH + head) * NN + n] = vd;
    }
  }

  const int b   = m0 >> 11;
  const int n0  = m0 & (NN - 1);
  const int jc  = n0 >> 5;
  const int grp = (n0 >> 3) & 3;
  const int t   = (tid >> 4) & 3, fl = tid & 15;
  uint4 vv;
  vv.x = cvtpk(hv[0], hv[1]);
  vv.y = cvtpk(hv[2], hv[3]);
  vv.z = cvtpk(hv[4], hv[5]);
  vv.w = cvtpk(hv[6], hv[7]);
  const size_t chunk =
      (((size_t)(b * NH + head) * 64 + jc) * 4 + t) * 64 + (grp * 16 + fl);
  *(uint4*)(hB + chunk * 8) = vv;
}

// ---------------------------------------------------------------------------
// Kernel 2: fused mask + leakyrelu + softmax + P@H via MFMA 16x16x32 bf16.
// grid 512 x 512 thr (8 waves). Block = (b, 16 i-rows); wave = (head, j-half).
// adj bits staged ONCE up-front (4KB LDS, padded) -> main loop is BARRIER-FREE.
// 2 blocks/CU, 16 waves/CU; no VGPR bound (65..128 is free at this grid).
// XCD swizzle: b = (L&7)>>1 so each XCD's L2 holds one batch's hB.
// ---------------------------------------------------------------------------
__global__ __launch_bounds__(512) void k2_main(
    const int* __restrict__ adj, const ushort* __restrict__ hB,
    const float* __restrict__ s_src, const float* __restrict__ s_dst,
    float* __restrict__ out)
{
  const int tid = threadIdx.x;
  const int wv  = tid >> 6;
  const int h   = wv >> 1;            // head
  const int js  = wv & 1;             // j-half
  const int l   = tid & 63;
  const int L   = blockIdx.x;
  const int b    = (L & 7) >> 1;                 // 2 XCDs per batch
  const int iblk = ((L >> 3) << 1) + (L & 1);    // bijective
  const int i0   = iblk << 4;

  const int bh   = b * NH + h;
  const int r16  = l & 15;
  const int grp  = l >> 4;
  const int koff = grp << 3;

  __shared__ unsigned abits[16][65];      // 16 rows x 2048 bits, padded
  __shared__ float red[NH][5][4][64];     // 20KB epilogue, stride-1/lane

  // ---- stage adj -> bits (once). thread: row = tid>>5, seg = tid&31 (64 j)
  {
    const int srow = tid >> 5, sseg = tid & 31;
    const int* sb = adj + ((size_t)(b * NN + i0 + srow)) * NN + sseg * 64;
    unsigned m[4];
    #pragma unroll
    for (int q = 0; q < 4; ++q) {
      const i32x4 a0 = *(const i32x4*)(sb + q * 16);
      const i32x4 a1 = *(const i32x4*)(sb + q * 16 + 4);
      const i32x4 a2 = *(const i32x4*)(sb + q * 16 + 8);
      const i32x4 a3 = *(const i32x4*)(sb + q * 16 + 12);
      m[q] = pack16(a0, a1, a2, a3);
    }
    abits[srow][sseg * 2]     = m[0] | (m[1] << 16);
    abits[srow][sseg * 2 + 1] = m[2] | (m[3] << 16);
  }
  __syncthreads();

  const float ssl = s_src[bh * NN + i0 + r16];
  const float*  sdp = s_dst + bh * NN;
  const ushort* hbW = hB + (size_t)bh * 131072 + l * 8;

  const short8 ones = {(short)0x3F80, (short)0x3F80, (short)0x3F80, (short)0x3F80,
                       (short)0x3F80, (short)0x3F80, (short)0x3F80, (short)0x3F80};

  f32x4 acc[4];
  #pragma unroll
  for (int q = 0; q < 4; ++q) acc[q] = (f32x4){0.f, 0.f, 0.f, 0.f};
  f32x4 acd = (f32x4){0.f, 0.f, 0.f, 0.f};

  // ---- main loop: 32 jc iterations, NO barriers
  #pragma unroll 2
  for (int jc = js * 32; jc < js * 32 + 32; ++jc) {
    const unsigned msk = abits[r16][jc] >> koff;
    const int jb = jc * 32 + koff;
    const f32x4 sd0 = *(const f32x4*)(sdp + jb);
    const f32x4 sd1 = *(const f32x4*)(sdp + jb + 4);
    const ushort* hc = hbW + jc * 2048;
    const short8 hb0 = *(const short8*)(hc);
    const short8 hb1 = *(const short8*)(hc + 512);
    const short8 hb2 = *(const short8*)(hc + 1024);
    const short8 hb3 = *(const short8*)(hc + 1536);

    float pl[8];
    #pragma unroll
    for (int e = 0; e < 8; ++e) {
      const float sdv = (e < 4) ? sd0[e] : sd1[e - 4];
      float x = ssl + sdv;                 // pre-scaled by log2(e)
      x = fmaxf(x, 0.2f * x);
      const float p = __builtin_amdgcn_exp2f(x);
      pl[e] = ((msk >> e) & 1u) ? p : 0.f;
    }
    u32x4 pa;
    #pragma unroll
    for (int e2 = 0; e2 < 4; ++e2) pa[e2] = cvtpk(pl[2 * e2], pl[2 * e2 + 1]);
    union { u32x4 u; short8 s; } ca; ca.u = pa;
    const short8 pal = ca.s;

    acc[0] = __builtin_amdgcn_mfma_f32_16x16x32_bf16(pal, hb0, acc[0], 0, 0, 0);
    acc[1] = __builtin_amdgcn_mfma_f32_16x16x32_bf16(pal, hb1, acc[1], 0, 0, 0);
    acc[2] = __builtin_amdgcn_mfma_f32_16x16x32_bf16(pal, hb2, acc[2], 0, 0, 0);
    acc[3] = __builtin_amdgcn_mfma_f32_16x16x32_bf16(pal, hb3, acc[3], 0, 0, 0);
    acd    = __builtin_amdgcn_mfma_f32_16x16x32_bf16(pal, ones, acd,    0, 0, 0);
  }

  // ---- 2-way js reduction: one barrier
  if (js) {
    #pragma unroll
    for (int t = 0; t < 4; ++t)
      #pragma unroll
      for (int r = 0; r < 4; ++r) red[h][t][r][l] = acc[t][r];
    #pragma unroll
    for (int r = 0; r < 4; ++r) red[h][4][r][l] = acd[r];
  }
  __syncthreads();

  if (!js) {
    #pragma unroll
    for (int t = 0; t < 4; ++t)
      #pragma unroll
      for (int r = 0; r < 4; ++r) acc[t][r] += red[h][t][r][l];
    #pragma unroll
    for (int r = 0; r < 4; ++r) acd[r] += red[h][4][r][l];

    float rl[4];
    #pragma unroll
    for (int r = 0; r < 4; ++r) rl[r] = 1.0f / acd[r];
    #pragma unroll
    for (int t = 0; t < 4; ++t) {
      #pragma unroll
      for (int r = 0; r < 4; ++r) {
        const int i = i0 + grp * 4 + r;
        const size_t oidx = ((size_t)(b * NN + i) * COLS) + h * 64 + t * 16 + r16;
        out[oidx] = acc[t][r] * rl[r];
      }
    }
  }
}

// ---------------------------------------------------------------------------
extern "C" void kernel_launch(void* const* d_in, const int* in_sizes, int n_in,
                              void* d_out, int out_size, void* d_ws, size_t ws_size,
                              hipStream_t stream) {
  const float* nf  = (const float*)d_in[0];
  const int*   adj = (const int*)d_in[1];
  const float* W   = (const float*)d_in[2];
  const float* att = (const float*)d_in[3];

  ushort* hB    = (ushort*)d_ws;                                  // 4 MB
  float*  s_src = (float*)((char*)d_ws + (size_t)16 * 64 * NN * 2);
  float*  s_dst = s_src + 16 * NN;

  hipLaunchKernelGGL(k1_prep, dim3(1024), dim3(256), 0, stream,
                     nf, W, att, hB, s_src, s_dst);
  hipLaunchKernelGGL(k2_main, dim3(512), dim3(512), 0, stream,
                     adj, hB, s_src, s_dst, (float*)d_out);
}